// Round 10
// baseline (906.689 us; speedup 1.0000x reference)
//
#include <hip/hip_runtime.h>
#include <hip/hip_cooperative_groups.h>
#include <math.h>

namespace cg = cooperative_groups;

#define Nn 50000
#define Ee 600000
#define Bg 128      // batches (graphs)
#define Hd 128      // hidden dim
#define Kt 30       // sortpool K
#define CO 32       // conv out channels
#define KW 5        // conv kernel
#define LOUT 26     // K - KW + 1
#define CAP 2048    // per-batch node cap for topk LDS (max real count ~460)
#define CG_B 1024   // cooperative grid blocks (4/CU at 256 CUs)

typedef float v2f __attribute__((ext_vector_type(2)));
typedef short bf16x8 __attribute__((ext_vector_type(8)));
typedef float f32x4 __attribute__((ext_vector_type(4)));

// bf16 round-to-nearest-even helpers (branchless, finite inputs)
__device__ __forceinline__ unsigned short bfr(float v) {
    unsigned u = __builtin_bit_cast(unsigned, v);
    unsigned r = (u + 0x7FFFu + ((u >> 16) & 1u)) >> 16;
    return (unsigned short)r;
}
__device__ __forceinline__ float bff(unsigned short h) {
    unsigned u = ((unsigned)h) << 16;
    return __builtin_bit_cast(float, u);
}

// ---------------- init + conv_w transpose + W 3-way split/pack ----------------
__global__ void initwprep_kernel(int* __restrict__ deg_i, int* __restrict__ cnt,
                            int* __restrict__ bstart,
                            const float* __restrict__ conv_w, float* __restrict__ wT2,
                            const float* __restrict__ W0, const float* __restrict__ W1,
                            const float* __restrict__ W2,
                            ushort* __restrict__ Bph, ushort* __restrict__ Bpm,
                            ushort* __restrict__ Bpl) {
    int i = blockIdx.x * 256 + threadIdx.x;
    if (i < Nn) { deg_i[i] = 1; cnt[i] = 0; }   // deg starts at 1 (self loop)
    if (i <= Bg) bstart[i] = Nn;                // sentinel
    if (i < CO * KW * Hd) {                     // wT2[o][k][ci] = conv_w[o][ci][k]
        int ci = i & 127;
        int r = i >> 7;          // o*KW + k
        int o = r / KW, k = r - o * KW;
        wT2[i] = conv_w[((size_t)o * Hd + ci) * KW + k];
    }
    if (i < 3 * 2048) {                          // W split+pack, B-fragment layout
        int l = i >> 11;
        int r = i & 2047;
        int kc = r >> 9;
        int n = (r >> 6) & 7;
        int lane = r & 63;
        int m = lane & 15, kq = lane >> 4;
        const float* W = (l == 0) ? W0 : (l == 1) ? W1 : W2;
        int col = n * 16 + m;
        size_t off = ((size_t)l * 2048 + (size_t)((kc * 8 + n) * 64 + lane)) * 8;
#pragma unroll
        for (int j = 0; j < 8; ++j) {
            float v = W[(size_t)(kc * 32 + kq * 8 + j) * Hd + col];
            unsigned short h = bfr(v);
            float r1 = v - bff(h);
            unsigned short mid = bfr(r1);
            Bph[off + j] = h;
            Bpm[off + j] = mid;
            Bpl[off + j] = bfr(r1 - bff(mid));
        }
    }
}

// ---------------- cooperative CSR build: count -> scanA -> scanB -> scanC -> fill ----
// one dispatch, grid.sync() between phases (replaces 5 dispatches + gaps)
__global__ __launch_bounds__(256, 4) void csr_coop(
        const int* __restrict__ ei, const int* __restrict__ batch,
        int* __restrict__ deg_i, int* __restrict__ bstart,
        float* __restrict__ dinv, int* __restrict__ bsum, int* __restrict__ boff,
        int* __restrict__ row_ptr, int* __restrict__ cnt, int* __restrict__ csr_src) {
    cg::grid_group grid = cg::this_grid();
    int tid = threadIdx.x;
    int gtid = blockIdx.x * 256 + tid;
    const int T = CG_B * 256;
    __shared__ int ls[256];

    // phase 1: degree histogram + batch starts (boundary detect)
    for (int i = gtid; i < Ee; i += T)
        atomicAdd(&deg_i[ei[Ee + i]], 1);                 // col = edge_index[1]
    for (int i = gtid; i < Nn; i += T) {
        int b = batch[i];
        if (i == 0) bstart[b] = 0;
        else if (batch[i - 1] != b) bstart[b] = i;
    }
    grid.sync();

    // phase 2: per-block sums of (deg-1), dinv  (blocks 0..195 have data)
    {
        int v = 0;
        if (gtid < Nn) {
            int d = deg_i[gtid];
            dinv[gtid] = 1.0f / sqrtf((float)d);
            v = d - 1;
        }
        ls[tid] = v;
        __syncthreads();
        for (int off = 128; off > 0; off >>= 1) {
            if (tid < off) ls[tid] += ls[tid + off];
            __syncthreads();
        }
        if (tid == 0) bsum[blockIdx.x] = ls[0];
    }
    grid.sync();

    // phase 3: block 0 scans the 1024 block sums -> exclusive boff; fix bstart
    if (blockIdx.x == 0) {
        int base = tid * 4;
        int s0 = bsum[base], s1 = bsum[base + 1], s2 = bsum[base + 2], s3 = bsum[base + 3];
        ls[tid] = s0 + s1 + s2 + s3;
        __syncthreads();
        for (int off = 1; off < 256; off <<= 1) {
            int v = (tid >= off) ? ls[tid - off] : 0;
            __syncthreads();
            ls[tid] += v;
            __syncthreads();
        }
        int excl = (tid > 0) ? ls[tid - 1] : 0;
        boff[base]     = excl;
        boff[base + 1] = excl + s0;
        boff[base + 2] = excl + s0 + s1;
        boff[base + 3] = excl + s0 + s1 + s2;
        if (tid == 0) {   // empty batches inherit next start (batch sorted)
            for (int b = Bg - 1; b >= 0; --b)
                if (bstart[b] == Nn) bstart[b] = bstart[b + 1];
        }
    }
    grid.sync();

    // phase 4: row_ptr = block offset + local inclusive scan
    {
        int v = (gtid < Nn) ? deg_i[gtid] - 1 : 0;
        ls[tid] = v;
        __syncthreads();
        for (int off = 1; off < 256; off <<= 1) {
            int t2 = (tid >= off) ? ls[tid - off] : 0;
            __syncthreads();
            ls[tid] += t2;
            __syncthreads();
        }
        if (gtid < Nn) row_ptr[gtid + 1] = ls[tid] + boff[blockIdx.x];
        if (gtid == 0) row_ptr[0] = 0;
    }
    grid.sync();

    // phase 5: CSR fill (edges grouped by destination col)
    for (int e = gtid; e < Ee; e += T) {
        int c = ei[Ee + e];
        int r = ei[e];
        int p = row_ptr[c] + atomicAdd(&cnt[c], 1);
        csr_src[p] = r;
    }
}

// ---------------- MFMA matmul: hw[i] = dinv[i] * (Hin[i] @ W) ----------------
// 3-way split-bf16 (near-fp32). Retained products: a0b0,a1b0,a0b1,a1b1,a2b0,a0b2.
__global__ __launch_bounds__(256) void mmx_kernel(const float* __restrict__ Hin,
                            const ushort* __restrict__ Bph, const ushort* __restrict__ Bpm,
                            const ushort* __restrict__ Bpl,
                            const float* __restrict__ dinv, float* __restrict__ hw) {
    int tid = threadIdx.x;
    int w = tid >> 6, lane = tid & 63;
    int m = lane & 15, kq = lane >> 4;
    int rowA = blockIdx.x * 64 + w * 16 + m;
    bool va = rowA < Nn;
    const float* ap = Hin + (size_t)rowA * Hd;
    f32x4 acc[8];
#pragma unroll
    for (int n = 0; n < 8; ++n) acc[n] = (f32x4)0.f;
#pragma unroll
    for (int kc = 0; kc < 4; ++kc) {
        bf16x8 a0 = (bf16x8)0, a1 = (bf16x8)0, a2 = (bf16x8)0;
        if (va) {
            float av[8];
            *(float4*)&av[0] = *(const float4*)(ap + kc * 32 + kq * 8);
            *(float4*)&av[4] = *(const float4*)(ap + kc * 32 + kq * 8 + 4);
#pragma unroll
            for (int j = 0; j < 8; ++j) {
                unsigned short h = bfr(av[j]);
                float r1 = av[j] - bff(h);
                unsigned short mid = bfr(r1);
                a0[j] = (short)h;
                a1[j] = (short)mid;
                a2[j] = (short)bfr(r1 - bff(mid));
            }
        }
        const ushort* bhp = Bph + (size_t)((kc * 8) * 64 + lane) * 8;
        const ushort* bmp = Bpm + (size_t)((kc * 8) * 64 + lane) * 8;
        const ushort* blp = Bpl + (size_t)((kc * 8) * 64 + lane) * 8;
#pragma unroll
        for (int n = 0; n < 8; ++n) {
            bf16x8 b0 = *(const bf16x8*)(bhp + (size_t)n * 64 * 8);
            bf16x8 b1 = *(const bf16x8*)(bmp + (size_t)n * 64 * 8);
            bf16x8 b2 = *(const bf16x8*)(blp + (size_t)n * 64 * 8);
            acc[n] = __builtin_amdgcn_mfma_f32_16x16x32_bf16(a0, b0, acc[n], 0, 0, 0);
            acc[n] = __builtin_amdgcn_mfma_f32_16x16x32_bf16(a1, b0, acc[n], 0, 0, 0);
            acc[n] = __builtin_amdgcn_mfma_f32_16x16x32_bf16(a0, b1, acc[n], 0, 0, 0);
            acc[n] = __builtin_amdgcn_mfma_f32_16x16x32_bf16(a1, b1, acc[n], 0, 0, 0);
            acc[n] = __builtin_amdgcn_mfma_f32_16x16x32_bf16(a2, b0, acc[n], 0, 0, 0);
            acc[n] = __builtin_amdgcn_mfma_f32_16x16x32_bf16(a0, b2, acc[n], 0, 0, 0);
        }
    }
    int rbase = blockIdx.x * 64 + w * 16 + kq * 4;
#pragma unroll
    for (int reg = 0; reg < 4; ++reg) {
        int r = rbase + reg;
        if (r < Nn) {
            float s = dinv[r];
#pragma unroll
            for (int n = 0; n < 8; ++n)
                hw[(size_t)r * Hd + n * 16 + m] = acc[n][reg] * s;
        }
    }
}

// ---------------- aggregation: h[i] = relu(dinv[i]*(hw[i] + sum_src hw[src]) + b) ----
__global__ __launch_bounds__(256) void agg_kernel(const float* __restrict__ hw,
                            const int* __restrict__ row_ptr, const int* __restrict__ csr_src,
                            const float* __restrict__ dinv, const float* __restrict__ bias,
                            float* __restrict__ hout) {
    int node = blockIdx.x * 4 + (threadIdx.x >> 6);
    if (node >= Nn) return;
    int lane = threadIdx.x & 63;
    const v2f* hw2 = (const v2f*)hw;
    v2f a0 = hw2[(size_t)node * 64 + lane];   // self loop (hw pre-scaled by dinv[src])
    v2f a1 = 0.f, a2 = 0.f, a3 = 0.f;
    int e0 = row_ptr[node], e1 = row_ptr[node + 1];
    int e = e0;
    for (; e + 3 < e1; e += 4) {
        int s0 = __builtin_nontemporal_load(csr_src + e);
        int s1 = __builtin_nontemporal_load(csr_src + e + 1);
        int s2 = __builtin_nontemporal_load(csr_src + e + 2);
        int s3 = __builtin_nontemporal_load(csr_src + e + 3);
        a0 += hw2[(size_t)s0 * 64 + lane];
        a1 += hw2[(size_t)s1 * 64 + lane];
        a2 += hw2[(size_t)s2 * 64 + lane];
        a3 += hw2[(size_t)s3 * 64 + lane];
    }
    for (; e < e1; ++e) {
        int s0 = __builtin_nontemporal_load(csr_src + e);
        a0 += hw2[(size_t)s0 * 64 + lane];
    }
    v2f acc = (a0 + a1) + (a2 + a3);
    float d = dinv[node];
    v2f bv = ((const v2f*)bias)[lane];
    v2f o;
    o.x = fmaxf(fmaf(d, acc.x, bv.x), 0.f);
    o.y = fmaxf(fmaf(d, acc.y, bv.y), 0.f);
    ((v2f*)hout)[(size_t)node * 64 + lane] = o;
}

// ---------------- fused tail: topk -> pooled tile in LDS -> conv -> lin1 -> lin2 ----
__global__ __launch_bounds__(256) void tail_kernel(const float* __restrict__ h,
                            const int* __restrict__ bstart,
                            const float* __restrict__ wT2, const float* __restrict__ conv_b,
                            const float* __restrict__ l1w, const float* __restrict__ l1b,
                            const float* __restrict__ l2w, const float* __restrict__ l2b,
                            float* __restrict__ out) {
    __shared__ float vals[CAP];          // 8 KB
    __shared__ float xcl[Kt][130];       // 15.6 KB, padded rows
    __shared__ float fl[CO * LOUT];      // 3.3 KB
    __shared__ float pz[2][Hd];
    __shared__ float z[Hd];
    __shared__ float rv[4];
    __shared__ int ri[4];
    __shared__ int selS[Kt];
    int b = blockIdx.x, tid = threadIdx.x;

    // --- top-K select (descending last feature, tie: smaller idx) ---
    int s0 = bstart[b], s1 = bstart[b + 1];
    int n = s1 - s0;
    int nc = n < CAP ? n : CAP;
    for (int j = tid; j < nc; j += 256)
        vals[j] = h[(size_t)(s0 + j) * Hd + (Hd - 1)];
    __syncthreads();
    for (int k = 0; k < Kt; ++k) {
        float bv = -1.f;
        int bi = 0x7fffffff;
        for (int j = tid; j < nc; j += 256) {
            float v = vals[j];
            if (v > bv || (v == bv && j < bi)) { bv = v; bi = j; }
        }
        for (int off = 32; off > 0; off >>= 1) {
            float ov = __shfl_down(bv, off);
            int oi = __shfl_down(bi, off);
            if (ov > bv || (ov == bv && oi < bi)) { bv = ov; bi = oi; }
        }
        int wid = tid >> 6;
        if ((tid & 63) == 0) { rv[wid] = bv; ri[wid] = bi; }
        __syncthreads();
        if (tid == 0) {
            float fv = rv[0]; int fi = ri[0];
            for (int w = 1; w < 4; ++w) {
                if (rv[w] > fv || (rv[w] == fv && ri[w] < fi)) { fv = rv[w]; fi = ri[w]; }
            }
            if (k < n) {
                selS[k] = s0 + fi;
                vals[fi] = -1.f;   // relu output >= 0, so -1 can never win again
            } else {
                selS[k] = -1;
            }
        }
        __syncthreads();
    }
    // --- gather pooled tile straight into LDS ---
    for (int i = tid; i < Kt * Hd; i += 256) {
        int t = i >> 7, c = i & 127;
        int s = selS[t];
        xcl[t][c] = (s >= 0) ? h[(size_t)s * Hd + c] : 0.f;
    }
    __syncthreads();
    // --- conv: fl[o*26+t] = relu(conv_b[o] + xc . w) ---
    for (int oi = tid; oi < CO * LOUT; oi += 256) {
        int o = oi / LOUT, t = oi - o * LOUT;
        float acc = conv_b[o];
#pragma unroll
        for (int k = 0; k < KW; ++k) {
            const float* xr = &xcl[t + k][0];
            const float* wr = wT2 + ((size_t)o * KW + k) * Hd;
#pragma unroll 8
            for (int c4 = 0; c4 < 32; ++c4) {
                float2 xa = *(const float2*)(xr + c4 * 4);
                float2 xb = *(const float2*)(xr + c4 * 4 + 2);
                float4 wv = *(const float4*)(wr + c4 * 4);
                acc = fmaf(xa.x, wv.x, acc);
                acc = fmaf(xa.y, wv.y, acc);
                acc = fmaf(xb.x, wv.z, acc);
                acc = fmaf(xb.y, wv.w, acc);
            }
        }
        fl[oi] = fmaxf(acc, 0.f);
    }
    __syncthreads();
    // --- lin1 (2-half partials) + relu + lin2 ---
    int hh = tid & 127, half = tid >> 7;
    int m0 = half * 416;
    float acc = 0.f;
#pragma unroll 8
    for (int m = 0; m < 416; ++m)
        acc = fmaf(fl[m0 + m], l1w[(size_t)(m0 + m) * Hd + hh], acc);
    pz[half][hh] = acc;
    __syncthreads();
    if (tid < Hd)
        z[tid] = fmaxf(pz[0][tid] + pz[1][tid] + l1b[tid], 0.f);
    __syncthreads();
    if (tid < 10) {
        float a2 = l2b[tid];
        for (int j = 0; j < Hd; ++j)
            a2 = fmaf(z[j], l2w[j * 10 + tid], a2);
        out[b * 10 + tid] = a2;
    }
}

extern "C" void kernel_launch(void* const* d_in, const int* in_sizes, int n_in,
                              void* d_out, int out_size, void* d_ws, size_t ws_size,
                              hipStream_t stream) {
    const float* x      = (const float*)d_in[0];
    const int*   ei     = (const int*)d_in[1];
    const int*   batch  = (const int*)d_in[2];
    const float* W0     = (const float*)d_in[3];
    const float* b0     = (const float*)d_in[4];
    const float* W1     = (const float*)d_in[5];
    const float* b1     = (const float*)d_in[6];
    const float* W2     = (const float*)d_in[7];
    const float* b2     = (const float*)d_in[8];
    const float* conv_w = (const float*)d_in[9];
    const float* conv_b = (const float*)d_in[10];
    const float* l1w    = (const float*)d_in[11];
    const float* l1b    = (const float*)d_in[12];
    const float* l2w    = (const float*)d_in[13];
    const float* l2b    = (const float*)d_in[14];
    float* out = (float*)d_out;

    // workspace layout
    int* wsI = (int*)d_ws;
    size_t off = 0;
    int*   deg_i   = wsI + off; off += Nn;
    int*   cnt     = wsI + off; off += Nn;
    int*   row_ptr = wsI + off; off += 50004;
    int*   bstart  = wsI + off; off += 132;
    float* dinv    = (float*)(wsI + off); off += Nn;
    int*   bsum    = wsI + off; off += CG_B;
    int*   boff    = wsI + off; off += CG_B;
    int*   csr_src = wsI + off; off += Ee;
    off = (off + 3) & ~(size_t)3;        // 16B align
    ushort* Bph  = (ushort*)(wsI + off); off += 3 * 16384 / 2;   // packed W split hi
    ushort* Bpm  = (ushort*)(wsI + off); off += 3 * 16384 / 2;   // packed W split mid
    ushort* Bpl  = (ushort*)(wsI + off); off += 3 * 16384 / 2;   // packed W split lo
    float* hw    = (float*)(wsI + off); off += (size_t)Nn * Hd;
    float* hbuf  = (float*)(wsI + off); off += (size_t)Nn * Hd;
    float* wT2   = (float*)(wsI + off); off += CO * KW * Hd;

    // 1. init + W prep (one dispatch)
    initwprep_kernel<<<(Nn + 255) / 256, 256, 0, stream>>>(deg_i, cnt, bstart,
        conv_w, wT2, W0, W1, W2, Bph, Bpm, Bpl);

    // 2. cooperative CSR build (count/scan/fill in one dispatch)
    void* cargs[] = { (void*)&ei, (void*)&batch, (void*)&deg_i, (void*)&bstart,
                      (void*)&dinv, (void*)&bsum, (void*)&boff, (void*)&row_ptr,
                      (void*)&cnt, (void*)&csr_src };
    hipLaunchCooperativeKernel((const void*)csr_coop, dim3(CG_B), dim3(256),
                               cargs, 0, stream);

    // 3. three GCN layers (MFMA matmul + gather-aggregate)
    dim3 mmGrid((Nn + 63) / 64);
    dim3 aggGrid((Nn + 3) / 4);
    mmx_kernel<<<mmGrid, 256, 0, stream>>>(x, Bph, Bpm, Bpl, dinv, hw);
    agg_kernel<<<aggGrid, 256, 0, stream>>>(hw, row_ptr, csr_src, dinv, b0, hbuf);
    mmx_kernel<<<mmGrid, 256, 0, stream>>>(hbuf, Bph + 16384, Bpm + 16384, Bpl + 16384, dinv, hw);
    agg_kernel<<<aggGrid, 256, 0, stream>>>(hw, row_ptr, csr_src, dinv, b1, hbuf);
    mmx_kernel<<<mmGrid, 256, 0, stream>>>(hbuf, Bph + 32768, Bpm + 32768, Bpl + 32768, dinv, hw);
    agg_kernel<<<aggGrid, 256, 0, stream>>>(hw, row_ptr, csr_src, dinv, b2, hbuf);

    // 4. fused tail: topk + conv + lin1 + lin2 (one dispatch)
    tail_kernel<<<Bg, 256, 0, stream>>>(hbuf, bstart, wT2, conv_b,
                                        l1w, l1b, l2w, l2b, out);
}

// Round 11
// 495.192 us; speedup vs baseline: 1.8310x; 1.8310x over previous
//
#include <hip/hip_runtime.h>
#include <math.h>

#define Nn 50000
#define Ee 600000
#define Bg 128      // batches (graphs)
#define Hd 128      // hidden dim
#define Kt 30       // sortpool K
#define CO 32       // conv out channels
#define KW 5        // conv kernel
#define LOUT 26     // K - KW + 1
#define CAP 2048    // per-batch node cap for topk LDS (max real count ~460)
#define SCB 196     // ceil(50000/256) scan blocks

typedef float v2f __attribute__((ext_vector_type(2)));
typedef short bf16x8 __attribute__((ext_vector_type(8)));
typedef float f32x4 __attribute__((ext_vector_type(4)));

// bf16 round-to-nearest-even helpers (branchless, finite inputs)
__device__ __forceinline__ unsigned short bfr(float v) {
    unsigned u = __builtin_bit_cast(unsigned, v);
    unsigned r = (u + 0x7FFFu + ((u >> 16) & 1u)) >> 16;
    return (unsigned short)r;
}
__device__ __forceinline__ float bff(unsigned short h) {
    unsigned u = ((unsigned)h) << 16;
    return __builtin_bit_cast(float, u);
}

// ---------------- init + conv_w transpose + W 3-way split/pack ----------------
__global__ void initwprep_kernel(int* __restrict__ deg_i, int* __restrict__ cnt,
                            int* __restrict__ bstart,
                            const float* __restrict__ conv_w, float* __restrict__ wT2,
                            const float* __restrict__ W0, const float* __restrict__ W1,
                            const float* __restrict__ W2,
                            ushort* __restrict__ Bph, ushort* __restrict__ Bpm,
                            ushort* __restrict__ Bpl) {
    int i = blockIdx.x * 256 + threadIdx.x;
    if (i < Nn) { deg_i[i] = 1; cnt[i] = 0; }   // deg starts at 1 (self loop)
    if (i <= Bg) bstart[i] = Nn;                // sentinel
    if (i < CO * KW * Hd) {                     // wT2[o][k][ci] = conv_w[o][ci][k]
        int ci = i & 127;
        int r = i >> 7;          // o*KW + k
        int o = r / KW, k = r - o * KW;
        wT2[i] = conv_w[((size_t)o * Hd + ci) * KW + k];
    }
    if (i < 3 * 2048) {                          // W split+pack, B-fragment layout
        int l = i >> 11;
        int r = i & 2047;
        int kc = r >> 9;
        int n = (r >> 6) & 7;
        int lane = r & 63;
        int m = lane & 15, kq = lane >> 4;
        const float* W = (l == 0) ? W0 : (l == 1) ? W1 : W2;
        int col = n * 16 + m;
        size_t off = ((size_t)l * 2048 + (size_t)((kc * 8 + n) * 64 + lane)) * 8;
#pragma unroll
        for (int j = 0; j < 8; ++j) {
            float v = W[(size_t)(kc * 32 + kq * 8 + j) * Hd + col];
            unsigned short h = bfr(v);
            float r1 = v - bff(h);
            unsigned short mid = bfr(r1);
            Bph[off + j] = h;
            Bpm[off + j] = mid;
            Bpl[off + j] = bfr(r1 - bff(mid));
        }
    }
}

// ---------------- degree histogram + batch starts (boundary detect) ----------
__global__ void count_kernel(const int* __restrict__ ei, const int* __restrict__ batch,
                             int* __restrict__ deg_i, int* __restrict__ bstart) {
    int i = blockIdx.x * 256 + threadIdx.x;
    if (i < Ee) atomicAdd(&deg_i[ei[Ee + i]], 1);       // col = edge_index[1]
    if (i < Nn) {
        int b = batch[i];
        if (i == 0) {
            bstart[b] = 0;
        } else {
            int bp = batch[i - 1];
            if (bp != b) bstart[b] = i;
        }
    }
}

// ---------------- scan phase A: block sums of (deg-1), dinv ----------------
__global__ __launch_bounds__(256) void scanA_kernel(const int* __restrict__ deg_i,
                            float* __restrict__ dinv, int* __restrict__ bsum) {
    __shared__ int s[256];
    int tid = threadIdx.x;
    int i = blockIdx.x * 256 + tid;
    int v = 0;
    if (i < Nn) {
        int d = deg_i[i];
        dinv[i] = 1.0f / sqrtf((float)d);
        v = d - 1;
    }
    s[tid] = v;
    __syncthreads();
    for (int off = 128; off > 0; off >>= 1) {
        if (tid < off) s[tid] += s[tid + off];
        __syncthreads();
    }
    if (tid == 0) bsum[blockIdx.x] = s[0];
}

// ---------------- scan phase B: scan block sums; fix empty batches ----------
__global__ __launch_bounds__(256) void scanB_kernel(const int* __restrict__ bsum,
                            int* __restrict__ boff, int* __restrict__ bstart) {
    __shared__ int s[256];
    int tid = threadIdx.x;
    int v = (tid < SCB) ? bsum[tid] : 0;
    s[tid] = v;
    __syncthreads();
    for (int off = 1; off < 256; off <<= 1) {
        int t = (tid >= off) ? s[tid - off] : 0;
        __syncthreads();
        s[tid] += t;
        __syncthreads();
    }
    if (tid < SCB) boff[tid] = s[tid] - v;   // exclusive
    if (tid == 0) {   // empty batches inherit next start (batch array sorted)
        for (int b = Bg - 1; b >= 0; --b)
            if (bstart[b] == Nn) bstart[b] = bstart[b + 1];
    }
}

// ---------------- scan phase C: row_ptr = offset + local inclusive scan -----
__global__ __launch_bounds__(256) void scanC_kernel(const int* __restrict__ deg_i,
                            const int* __restrict__ boff, int* __restrict__ row_ptr) {
    __shared__ int s[256];
    int tid = threadIdx.x;
    int i = blockIdx.x * 256 + tid;
    int v = (i < Nn) ? deg_i[i] - 1 : 0;
    s[tid] = v;
    __syncthreads();
    for (int off = 1; off < 256; off <<= 1) {
        int t = (tid >= off) ? s[tid - off] : 0;
        __syncthreads();
        s[tid] += t;
        __syncthreads();
    }
    if (i < Nn) row_ptr[i + 1] = s[tid] + boff[blockIdx.x];
    if (i == 0) row_ptr[0] = 0;
}

// ---------------- CSR fill (edges grouped by destination col) ----------------
__global__ void fill_kernel(const int* __restrict__ ei, const int* __restrict__ row_ptr,
                            int* __restrict__ cnt, int* __restrict__ csr_src) {
    int e = blockIdx.x * 256 + threadIdx.x;
    if (e >= Ee) return;
    int c = ei[Ee + e];
    int r = ei[e];
    int p = row_ptr[c] + atomicAdd(&cnt[c], 1);
    csr_src[p] = r;
}

// ---------------- MFMA matmul: hw[i] = dinv[i] * (Hin[i] @ W) ----------------
// 3-way split-bf16 (near-fp32). Retained products: a0b0,a1b0,a0b1,a1b1,a2b0,a0b2.
__global__ __launch_bounds__(256) void mmx_kernel(const float* __restrict__ Hin,
                            const ushort* __restrict__ Bph, const ushort* __restrict__ Bpm,
                            const ushort* __restrict__ Bpl,
                            const float* __restrict__ dinv, float* __restrict__ hw) {
    int tid = threadIdx.x;
    int w = tid >> 6, lane = tid & 63;
    int m = lane & 15, kq = lane >> 4;
    int rowA = blockIdx.x * 64 + w * 16 + m;
    bool va = rowA < Nn;
    const float* ap = Hin + (size_t)rowA * Hd;
    f32x4 acc[8];
#pragma unroll
    for (int n = 0; n < 8; ++n) acc[n] = (f32x4)0.f;
#pragma unroll
    for (int kc = 0; kc < 4; ++kc) {
        bf16x8 a0 = (bf16x8)0, a1 = (bf16x8)0, a2 = (bf16x8)0;
        if (va) {
            float av[8];
            *(float4*)&av[0] = *(const float4*)(ap + kc * 32 + kq * 8);
            *(float4*)&av[4] = *(const float4*)(ap + kc * 32 + kq * 8 + 4);
#pragma unroll
            for (int j = 0; j < 8; ++j) {
                unsigned short h = bfr(av[j]);
                float r1 = av[j] - bff(h);
                unsigned short mid = bfr(r1);
                a0[j] = (short)h;
                a1[j] = (short)mid;
                a2[j] = (short)bfr(r1 - bff(mid));
            }
        }
        const ushort* bhp = Bph + (size_t)((kc * 8) * 64 + lane) * 8;
        const ushort* bmp = Bpm + (size_t)((kc * 8) * 64 + lane) * 8;
        const ushort* blp = Bpl + (size_t)((kc * 8) * 64 + lane) * 8;
#pragma unroll
        for (int n = 0; n < 8; ++n) {
            bf16x8 b0 = *(const bf16x8*)(bhp + (size_t)n * 64 * 8);
            bf16x8 b1 = *(const bf16x8*)(bmp + (size_t)n * 64 * 8);
            bf16x8 b2 = *(const bf16x8*)(blp + (size_t)n * 64 * 8);
            acc[n] = __builtin_amdgcn_mfma_f32_16x16x32_bf16(a0, b0, acc[n], 0, 0, 0);
            acc[n] = __builtin_amdgcn_mfma_f32_16x16x32_bf16(a1, b0, acc[n], 0, 0, 0);
            acc[n] = __builtin_amdgcn_mfma_f32_16x16x32_bf16(a0, b1, acc[n], 0, 0, 0);
            acc[n] = __builtin_amdgcn_mfma_f32_16x16x32_bf16(a1, b1, acc[n], 0, 0, 0);
            acc[n] = __builtin_amdgcn_mfma_f32_16x16x32_bf16(a2, b0, acc[n], 0, 0, 0);
            acc[n] = __builtin_amdgcn_mfma_f32_16x16x32_bf16(a0, b2, acc[n], 0, 0, 0);
        }
    }
    int rbase = blockIdx.x * 64 + w * 16 + kq * 4;
#pragma unroll
    for (int reg = 0; reg < 4; ++reg) {
        int r = rbase + reg;
        if (r < Nn) {
            float s = dinv[r];
#pragma unroll
            for (int n = 0; n < 8; ++n)
                hw[(size_t)r * Hd + n * 16 + m] = acc[n][reg] * s;
        }
    }
}

// ---------------- aggregation: h[i] = relu(dinv[i]*(hw[i] + sum_src hw[src]) + b) ----
__global__ __launch_bounds__(256) void agg_kernel(const float* __restrict__ hw,
                            const int* __restrict__ row_ptr, const int* __restrict__ csr_src,
                            const float* __restrict__ dinv, const float* __restrict__ bias,
                            float* __restrict__ hout) {
    int node = blockIdx.x * 4 + (threadIdx.x >> 6);
    if (node >= Nn) return;
    int lane = threadIdx.x & 63;
    const v2f* hw2 = (const v2f*)hw;
    v2f a0 = hw2[(size_t)node * 64 + lane];   // self loop (hw pre-scaled by dinv[src])
    v2f a1 = 0.f, a2 = 0.f, a3 = 0.f;
    int e0 = row_ptr[node], e1 = row_ptr[node + 1];
    int e = e0;
    for (; e + 3 < e1; e += 4) {
        int s0 = __builtin_nontemporal_load(csr_src + e);
        int s1 = __builtin_nontemporal_load(csr_src + e + 1);
        int s2 = __builtin_nontemporal_load(csr_src + e + 2);
        int s3 = __builtin_nontemporal_load(csr_src + e + 3);
        a0 += hw2[(size_t)s0 * 64 + lane];
        a1 += hw2[(size_t)s1 * 64 + lane];
        a2 += hw2[(size_t)s2 * 64 + lane];
        a3 += hw2[(size_t)s3 * 64 + lane];
    }
    for (; e < e1; ++e) {
        int s0 = __builtin_nontemporal_load(csr_src + e);
        a0 += hw2[(size_t)s0 * 64 + lane];
    }
    v2f acc = (a0 + a1) + (a2 + a3);
    float d = dinv[node];
    v2f bv = ((const v2f*)bias)[lane];
    v2f o;
    o.x = fmaxf(fmaf(d, acc.x, bv.x), 0.f);
    o.y = fmaxf(fmaf(d, acc.y, bv.y), 0.f);
    ((v2f*)hout)[(size_t)node * 64 + lane] = o;
}

// ---------------- fused tail: topk -> pooled tile in LDS -> conv -> lin1 -> lin2 ----
__global__ __launch_bounds__(256) void tail_kernel(const float* __restrict__ h,
                            const int* __restrict__ bstart,
                            const float* __restrict__ wT2, const float* __restrict__ conv_b,
                            const float* __restrict__ l1w, const float* __restrict__ l1b,
                            const float* __restrict__ l2w, const float* __restrict__ l2b,
                            float* __restrict__ out) {
    __shared__ float vals[CAP];          // 8 KB
    __shared__ float xcl[Kt][130];       // 15.6 KB, padded rows
    __shared__ float fl[CO * LOUT];      // 3.3 KB
    __shared__ float pz[2][Hd];
    __shared__ float z[Hd];
    __shared__ float rv[4];
    __shared__ int ri[4];
    __shared__ int selS[Kt];
    int b = blockIdx.x, tid = threadIdx.x;

    // --- top-K select (descending last feature, tie: smaller idx) ---
    int s0 = bstart[b], s1 = bstart[b + 1];
    int n = s1 - s0;
    int nc = n < CAP ? n : CAP;
    for (int j = tid; j < nc; j += 256)
        vals[j] = h[(size_t)(s0 + j) * Hd + (Hd - 1)];
    __syncthreads();
    for (int k = 0; k < Kt; ++k) {
        float bv = -1.f;
        int bi = 0x7fffffff;
        for (int j = tid; j < nc; j += 256) {
            float v = vals[j];
            if (v > bv || (v == bv && j < bi)) { bv = v; bi = j; }
        }
        for (int off = 32; off > 0; off >>= 1) {
            float ov = __shfl_down(bv, off);
            int oi = __shfl_down(bi, off);
            if (ov > bv || (ov == bv && oi < bi)) { bv = ov; bi = oi; }
        }
        int wid = tid >> 6;
        if ((tid & 63) == 0) { rv[wid] = bv; ri[wid] = bi; }
        __syncthreads();
        if (tid == 0) {
            float fv = rv[0]; int fi = ri[0];
            for (int w = 1; w < 4; ++w) {
                if (rv[w] > fv || (rv[w] == fv && ri[w] < fi)) { fv = rv[w]; fi = ri[w]; }
            }
            if (k < n) {
                selS[k] = s0 + fi;
                vals[fi] = -1.f;   // relu output >= 0, so -1 can never win again
            } else {
                selS[k] = -1;
            }
        }
        __syncthreads();
    }
    // --- gather pooled tile straight into LDS ---
    for (int i = tid; i < Kt * Hd; i += 256) {
        int t = i >> 7, c = i & 127;
        int s = selS[t];
        xcl[t][c] = (s >= 0) ? h[(size_t)s * Hd + c] : 0.f;
    }
    __syncthreads();
    // --- conv: fl[o*26+t] = relu(conv_b[o] + xc . w) ---
    for (int oi = tid; oi < CO * LOUT; oi += 256) {
        int o = oi / LOUT, t = oi - o * LOUT;
        float acc = conv_b[o];
#pragma unroll
        for (int k = 0; k < KW; ++k) {
            const float* xr = &xcl[t + k][0];
            const float* wr = wT2 + ((size_t)o * KW + k) * Hd;
#pragma unroll 8
            for (int c4 = 0; c4 < 32; ++c4) {
                float2 xa = *(const float2*)(xr + c4 * 4);
                float2 xb = *(const float2*)(xr + c4 * 4 + 2);
                float4 wv = *(const float4*)(wr + c4 * 4);
                acc = fmaf(xa.x, wv.x, acc);
                acc = fmaf(xa.y, wv.y, acc);
                acc = fmaf(xb.x, wv.z, acc);
                acc = fmaf(xb.y, wv.w, acc);
            }
        }
        fl[oi] = fmaxf(acc, 0.f);
    }
    __syncthreads();
    // --- lin1 (2-half partials) + relu + lin2 ---
    int hh = tid & 127, half = tid >> 7;
    int m0 = half * 416;
    float acc = 0.f;
#pragma unroll 8
    for (int m = 0; m < 416; ++m)
        acc = fmaf(fl[m0 + m], l1w[(size_t)(m0 + m) * Hd + hh], acc);
    pz[half][hh] = acc;
    __syncthreads();
    if (tid < Hd)
        z[tid] = fmaxf(pz[0][tid] + pz[1][tid] + l1b[tid], 0.f);
    __syncthreads();
    if (tid < 10) {
        float a2 = l2b[tid];
        for (int j = 0; j < Hd; ++j)
            a2 = fmaf(z[j], l2w[j * 10 + tid], a2);
        out[b * 10 + tid] = a2;
    }
}

extern "C" void kernel_launch(void* const* d_in, const int* in_sizes, int n_in,
                              void* d_out, int out_size, void* d_ws, size_t ws_size,
                              hipStream_t stream) {
    const float* x      = (const float*)d_in[0];
    const int*   ei     = (const int*)d_in[1];
    const int*   batch  = (const int*)d_in[2];
    const float* W0     = (const float*)d_in[3];
    const float* b0     = (const float*)d_in[4];
    const float* W1     = (const float*)d_in[5];
    const float* b1     = (const float*)d_in[6];
    const float* W2     = (const float*)d_in[7];
    const float* b2     = (const float*)d_in[8];
    const float* conv_w = (const float*)d_in[9];
    const float* conv_b = (const float*)d_in[10];
    const float* l1w    = (const float*)d_in[11];
    const float* l1b    = (const float*)d_in[12];
    const float* l2w    = (const float*)d_in[13];
    const float* l2b    = (const float*)d_in[14];
    float* out = (float*)d_out;

    // workspace layout
    int* wsI = (int*)d_ws;
    size_t off = 0;
    int*   deg_i   = wsI + off; off += Nn;
    int*   cnt     = wsI + off; off += Nn;
    int*   row_ptr = wsI + off; off += 50004;
    int*   bstart  = wsI + off; off += 132;
    float* dinv    = (float*)(wsI + off); off += Nn;
    int*   bsum    = wsI + off; off += 256;
    int*   boff    = wsI + off; off += 256;
    int*   csr_src = wsI + off; off += Ee;
    off = (off + 3) & ~(size_t)3;        // 16B align
    ushort* Bph  = (ushort*)(wsI + off); off += 3 * 16384 / 2;   // packed W split hi
    ushort* Bpm  = (ushort*)(wsI + off); off += 3 * 16384 / 2;   // packed W split mid
    ushort* Bpl  = (ushort*)(wsI + off); off += 3 * 16384 / 2;   // packed W split lo
    float* hw    = (float*)(wsI + off); off += (size_t)Nn * Hd;
    float* hbuf  = (float*)(wsI + off); off += (size_t)Nn * Hd;
    float* wT2   = (float*)(wsI + off); off += CO * KW * Hd;

    // 1. init + W prep (one dispatch)
    initwprep_kernel<<<(Nn + 255) / 256, 256, 0, stream>>>(deg_i, cnt, bstart,
        conv_w, wT2, W0, W1, W2, Bph, Bpm, Bpl);
    // 2. degree histogram + batch starts
    count_kernel<<<(Ee + 255) / 256, 256, 0, stream>>>(ei, batch, deg_i, bstart);
    // 3. multi-block exclusive scan -> row_ptr, dinv; fix bstart
    scanA_kernel<<<SCB, 256, 0, stream>>>(deg_i, dinv, bsum);
    scanB_kernel<<<1, 256, 0, stream>>>(bsum, boff, bstart);
    scanC_kernel<<<SCB, 256, 0, stream>>>(deg_i, boff, row_ptr);
    // 4. CSR fill
    fill_kernel<<<(Ee + 255) / 256, 256, 0, stream>>>(ei, row_ptr, cnt, csr_src);

    // 5. three GCN layers (MFMA matmul + gather-aggregate)
    dim3 mmGrid((Nn + 63) / 64);
    dim3 aggGrid((Nn + 3) / 4);
    mmx_kernel<<<mmGrid, 256, 0, stream>>>(x, Bph, Bpm, Bpl, dinv, hw);
    agg_kernel<<<aggGrid, 256, 0, stream>>>(hw, row_ptr, csr_src, dinv, b0, hbuf);
    mmx_kernel<<<mmGrid, 256, 0, stream>>>(hbuf, Bph + 16384, Bpm + 16384, Bpl + 16384, dinv, hw);
    agg_kernel<<<aggGrid, 256, 0, stream>>>(hw, row_ptr, csr_src, dinv, b1, hbuf);
    mmx_kernel<<<mmGrid, 256, 0, stream>>>(hbuf, Bph + 32768, Bpm + 32768, Bpl + 32768, dinv, hw);
    agg_kernel<<<aggGrid, 256, 0, stream>>>(hw, row_ptr, csr_src, dinv, b2, hbuf);

    // 6. fused tail: topk + conv + lin1 + lin2 (one dispatch)
    tail_kernel<<<Bg, 256, 0, stream>>>(hbuf, bstart, wT2, conv_b,
                                        l1w, l1b, l2w, l2b, out);
}